// Round 16
// baseline (186.351 us; speedup 1.0000x reference)
//
#include <hip/hip_runtime.h>

// Steerable pyramid via MFMA, fp32 I/O, bf16 compute (threshold = 2% of
// per-output absmax; bf16 error 16384 << 46202, verified r12-r15).
// CX layout for staged images: [n][y][c 16][x] bf16, zero-padded.
// r15 core (kept): 9-tap convs on mfma_f32_32x32x16_bf16 with fused M
// (bands: 4 bands x 8 px; dual: 2 rows x 2 filters x 8 px; K=16 window),
// down17 on 16x16x32 k-split. D map: col=l&31, row=(reg&3)+8(reg>>2)+4(l>>5).
// r16: launch fusion 12 -> 6. prep_all = build_frags+zero_pads+img_to_cx
// (grid-split). scale_comb<s> = bands+down (blockIdx split; down loads its
// A fragments per-dy from the L1-resident AF table to keep the fused
// kernel at the bands register class, __launch_bounds__(256,4)).

typedef __attribute__((ext_vector_type(8))) short short8v;
typedef __attribute__((ext_vector_type(4))) float f32x4;
typedef __attribute__((ext_vector_type(16))) float f32x16;

static __device__ __forceinline__ unsigned short f2bf(float f) {
    union { float f; unsigned u; } v; v.f = f;
    unsigned u = v.u;
    u += 0x7fffu + ((u >> 16) & 1u);
    return (unsigned short)(u >> 16);
}

static __device__ __forceinline__ unsigned pack2(float a, float b) {
    return (unsigned)f2bf(a) | ((unsigned)f2bf(b) << 16);
}

static __device__ __forceinline__ void nt_storef(float* p, float v) {
    __builtin_nontemporal_store(v, p);
}

// AF fragment table rows (entry = short8v per lane, row*64+l):
// [0..8] bands32 dy | [9..18] dual32 i | [19..35] down A1 | [36..52] down A2

// ---------------------------------------------------------------- prep

static __device__ __forceinline__ void do_build_frags(
    const float* bf, const float* fh, const float* fl, const float* lfilt,
    unsigned short* AF, int id)
{
    if (id >= 53 * 64) return;
    int row = id >> 6, l = id & 63;
    short8v a;
    if (row < 9) {
        int dy = row;
        int m = l & 31, f = m >> 3, p = m & 7, kb = (l >> 5) * 8;
        #pragma unroll
        for (int i = 0; i < 8; ++i) {
            int d = kb + i - p;
            a[i] = (short)((d >= 0 && d < 9) ? f2bf(bf[f * 81 + dy * 9 + d]) : 0);
        }
    } else if (row < 19) {
        int is = row - 9;
        int m = l & 31, ry = m >> 4, f = (m >> 3) & 1, p = m & 7, kb = (l >> 5) * 8;
        int dy = is - ry;
        const float* fr = f ? fl : fh;
        #pragma unroll
        for (int i = 0; i < 8; ++i) {
            int dx = kb + i - p;
            bool ok = (dy >= 0 && dy < 9) && (dx >= 0 && dx < 9);
            a[i] = (short)(ok ? f2bf(fr[dy * 9 + dx]) : 0);
        }
    } else if (row < 36) {
        int dy = row - 19;
        int m = l & 15, kb = (l >> 4) * 8;
        #pragma unroll
        for (int i = 0; i < 8; ++i) {
            int d = kb + i - 2 * m;
            a[i] = (short)((d >= 0 && d < 17) ? f2bf(lfilt[dy * 17 + d]) : 0);
        }
    } else {
        int dy = row - 36;
        int m = l & 15, kb = (l >> 4) * 8;
        #pragma unroll
        for (int i = 0; i < 8; ++i) {
            int d = 32 + kb + i - 2 * m;
            a[i] = (short)((d >= 0 && d < 17) ? f2bf(lfilt[dy * 17 + d]) : 0);
        }
    }
    *(short8v*)(AF + (size_t)id * 8) = a;
}

static __device__ __forceinline__ void zero_cx_vec(
    unsigned short* buf, int W, int id)
{
    int Wp = W + 16, Wv = Wp >> 3;
    int rowT = 16 * 16 * Wv;
    int perN = rowT + W * 32;
    int n = id / perN;
    int r = id - n * perN;
    int y, c, xv;
    if (r < rowT) {
        int ry = r / (16 * Wv);
        int rem = r - ry * (16 * Wv);
        c = rem / Wv;
        xv = rem - c * Wv;
        y = (ry < 8) ? ry : ry + W;
    } else {
        int r2 = r - rowT;
        y = 8 + (r2 >> 5);
        int rem = r2 & 31;
        c = rem >> 1;
        xv = (rem & 1) ? (Wv - 1) : 0;
    }
    short8v z = {0, 0, 0, 0, 0, 0, 0, 0};
    *(short8v*)(buf + ((size_t)(n * Wp + y) * 16 + c) * Wp + xv * 8) = z;
}

// prep_all: [0,14) build_frags | [14,1038) zero_pads | [1038,3150) img_to_cx.
__global__ __launch_bounds__(256) void prep_all(
    const float* __restrict__ bf, const float* __restrict__ fh,
    const float* __restrict__ fl, const float* __restrict__ lfilt,
    unsigned short* __restrict__ AF,
    unsigned short* __restrict__ L0, unsigned short* __restrict__ L1,
    unsigned short* __restrict__ L2, unsigned short* __restrict__ L3,
    const float4* __restrict__ src4, unsigned short* __restrict__ IMG)
{
    __shared__ unsigned short lds[16][264];
    int b = blockIdx.x, t = threadIdx.x;
    if (b < 14) {
        do_build_frags(bf, fh, fl, lfilt, AF, b * 256 + t);
    } else if (b < 1038) {
        int zb = b - 14;
        if (zb < 528)      zero_cx_vec(L0, 256, zb * 256 + t);
        else if (zb < 800) zero_cx_vec(L1, 128, (zb - 528) * 256 + t);
        else if (zb < 944) zero_cx_vec(L2, 64,  (zb - 800) * 256 + t);
        else               zero_cx_vec(L3, 32,  (zb - 944) * 256 + t);
    } else {
        int ib = b - 1038;                   // 2112 = 8 * 264
        int n = ib & 7;
        int yp = ib >> 3;
        int y = yp - 4;
        unsigned short* drow = IMG + ((size_t)(n * 264 + yp) * 16) * 264;
        if ((unsigned)y < 256u) {
            for (int task = t; task < 1056; task += 256) {
                int px = task >> 2, cg = task & 3;
                int xs = px - 4;
                bool ok = (unsigned)xs < 256u;
                int xc = min(max(xs, 0), 255);
                float4 v = src4[((size_t)(n * 256 + y) * 256 + xc) * 4 + cg];
                lds[cg * 4 + 0][px] = (unsigned short)(ok ? f2bf(v.x) : 0);
                lds[cg * 4 + 1][px] = (unsigned short)(ok ? f2bf(v.y) : 0);
                lds[cg * 4 + 2][px] = (unsigned short)(ok ? f2bf(v.z) : 0);
                lds[cg * 4 + 3][px] = (unsigned short)(ok ? f2bf(v.w) : 0);
            }
            __syncthreads();
            for (int task = t; task < 528; task += 256) {
                int c = task / 33, xg = task - c * 33;
                short8v v = *(const short8v*)&lds[c][xg * 8];
                *(short8v*)(drow + (size_t)c * 264 + xg * 8) = v;
            }
        } else {
            short8v z = {0, 0, 0, 0, 0, 0, 0, 0};
            for (int task = t; task < 528; task += 256) {
                int c = task / 33, xg = task - c * 33;
                *(short8v*)(drow + (size_t)c * 264 + xg * 8) = z;
            }
        }
    }
}

// ---------------------------------------------------------------- MFMA convs

#define MFMA16 __builtin_amdgcn_mfma_f32_16x16x32_bf16
#define MFMA32 __builtin_amdgcn_mfma_f32_32x32x16_bf16

// hi0 + lo0 from IMG CX (pad 4), 32x32x16, M = 2 rows x 2 filt x 8 px.
__global__ __launch_bounds__(256, 4) void dual_mfma32(
    const unsigned short* __restrict__ img,
    float* __restrict__ hi0, unsigned short* __restrict__ lo0,
    const unsigned short* __restrict__ AF)
{
    const int RS = 16 * 264;
    int n = blockIdx.x & 7;
    int q = blockIdx.x >> 3;
    int xseg = q & 15, yq = q >> 4;
    int t = threadIdx.x, wv = t >> 6, l = t & 63;
    int j = l & 31, pg = j >> 4, c = j & 15, kb = (l >> 5) * 8, hi = l >> 5;
    int x0 = xseg * 16;
    int pbase = (yq * 4 + wv) * 4;

    short8v A[10];
    #pragma unroll
    for (int i = 0; i < 10; ++i)
        A[i] = *(const short8v*)(AF + ((size_t)((9 + i) * 64 + l)) * 8);

    #pragma unroll 1
    for (int tp = 0; tp < 4; ++tp) {
        int y = (pbase + tp) * 2;
        const unsigned short* base =
            img + ((size_t)(n * 264 + y) * 16 + c) * 264 + x0 + pg * 8 + kb;
        f32x16 acc = {};
        #pragma unroll
        for (int i = 0; i < 10; ++i) {
            short8v B = *(const short8v*)(base + (size_t)i * RS);
            acc = MFMA32(A[i], B, acc, 0, 0, 0);
        }
        #pragma unroll
        for (int ry = 0; ry < 2; ++ry) {
            size_t hb = ((size_t)(n * 256 + y + ry) * 256 + x0 + pg * 8) * 16 + c;
            #pragma unroll
            for (int rr = 0; rr < 4; ++rr) {
                int r = ry * 8 + rr;
                int p = rr + 4 * hi;
                nt_storef(hi0 + hb + (size_t)p * 16, acc[r]);
            }
            size_t lb = ((size_t)(n * 272 + y + ry + 8) * 16 + c) * 272
                        + (x0 + pg * 8 + 4 * hi + 8);
            int r0 = ry * 8 + 4;
            *(unsigned*)(lo0 + lb)     = pack2(acc[r0],     acc[r0 + 1]);
            *(unsigned*)(lo0 + lb + 2) = pack2(acc[r0 + 2], acc[r0 + 3]);
        }
    }
}

// Fused per-scale: q < bandsPerN -> bands (32x32x16, A preloaded);
// else -> down17 (16x16x32, A loaded per-dy from AF to cap registers).
template <int LOGW, bool OUTF32>
__global__ __launch_bounds__(256, 4) void scale_comb(
    const unsigned short* __restrict__ in,
    float* __restrict__ b0, float* __restrict__ b1,
    float* __restrict__ b2, float* __restrict__ b3,
    void* __restrict__ lo_out,
    const unsigned short* __restrict__ AF)
{
    const int W = 1 << LOGW, Wp = W + 16, XS = W / 16, RS = 16 * Wp;
    const int Wo = W >> 1, Wpo = Wo + 16, XS2 = Wo / 16;
    const int bandsPerN = XS * XS;
    int n = blockIdx.x & 7;
    int q = blockIdx.x >> 3;
    int t = threadIdx.x, wv = t >> 6, l = t & 63;

    if (q < bandsPerN) {
        int xseg = q & (XS - 1), yq = q >> (LOGW - 4);
        int j = l & 31, pg = j >> 4, c = j & 15, kb = (l >> 5) * 8, hi = l >> 5;
        int x0 = xseg * 16;
        int ybase = (yq * 4 + wv) * 4;

        short8v A[9];
        #pragma unroll
        for (int dy = 0; dy < 9; ++dy)
            A[dy] = *(const short8v*)(AF + ((size_t)(dy * 64 + l)) * 8);

        #pragma unroll 1
        for (int ty = 0; ty < 4; ++ty) {
            int y = ybase + ty;
            const unsigned short* base =
                in + ((size_t)(n * Wp + y + 4) * 16 + c) * Wp + x0 + pg * 8 + kb + 4;
            f32x16 acc = {};
            #pragma unroll
            for (int dy = 0; dy < 9; ++dy) {
                short8v B = *(const short8v*)(base + (size_t)dy * RS);
                acc = MFMA32(A[dy], B, acc, 0, 0, 0);
            }
            size_t ob = ((size_t)(n * W + y) * W + x0 + pg * 8) * 16 + c;
            #pragma unroll
            for (int rr = 0; rr < 4; ++rr) {
                size_t o = ob + (size_t)(rr + 4 * hi) * 16;
                nt_storef(b0 + o, acc[rr]);
                nt_storef(b1 + o, acc[4 + rr]);
                nt_storef(b2 + o, acc[8 + rr]);
                nt_storef(b3 + o, acc[12 + rr]);
            }
        }
    } else {
        int q2 = q - bandsPerN;
        int xseg = q2 & (XS2 - 1), yq = q2 >> (LOGW - 5);
        int m = l & 15, g = l >> 4, kb = g * 8;
        int x0 = xseg * 16;
        int ybase = (yq * 4 + wv) * 4;
        int off2 = (g < 2) ? 32 : 0;

        #pragma unroll 1
        for (int ty = 0; ty < 4; ++ty) {
            int yo = ybase + ty;
            const unsigned short* base =
                in + ((size_t)(n * Wp + 2 * yo) * 16 + m) * Wp + 2 * x0 + kb;
            f32x4 aA = {0, 0, 0, 0}, aB = {0, 0, 0, 0};
            #pragma unroll
            for (int dy = 0; dy < 17; ++dy) {
                short8v A1 = *(const short8v*)(AF + ((size_t)((19 + dy) * 64 + l)) * 8);
                short8v A2 = *(const short8v*)(AF + ((size_t)((36 + dy) * 64 + l)) * 8);
                short8v B1 = *(const short8v*)(base + (size_t)dy * RS);
                short8v B2 = *(const short8v*)(base + (size_t)dy * RS + off2);
                aA = MFMA16(A1, B1, aA, 0, 0, 0);
                aB = MFMA16(A2, B2, aB, 0, 0, 0);
            }
            f32x4 acc = aA + aB;
            if (OUTF32) {
                float* o = (float*)lo_out;
                size_t ob = ((size_t)(n * Wo + yo) * Wo + x0 + g * 4) * 16 + m;
                #pragma unroll
                for (int r = 0; r < 4; ++r) nt_storef(o + ob + (size_t)r * 16, acc[r]);
            } else {
                unsigned short* o = (unsigned short*)lo_out;
                size_t lb = ((size_t)(n * Wpo + yo + 8) * 16 + m) * Wpo + (x0 + 8 + g * 4);
                *(unsigned*)(o + lb)     = pack2(acc[0], acc[1]);
                *(unsigned*)(o + lb + 2) = pack2(acc[2], acc[3]);
            }
        }
    }
}

// ---------------------------------------------------------------- launch

extern "C" void kernel_launch(void* const* d_in, const int* in_sizes, int n_in,
                              void* d_out, int out_size, void* d_ws, size_t ws_size,
                              hipStream_t stream) {
    const float* image   = (const float*)d_in[0];
    const float* lo0filt = (const float*)d_in[1];
    const float* hi0filt = (const float*)d_in[2];
    const float* lofilt  = (const float*)d_in[3];
    const float* bfilts  = (const float*)d_in[4];
    float* out = (float*)d_out;

    const int N = 8, C = 16;
    size_t sz[5];
    const int Ws[5] = {256, 128, 64, 32, 16};
    for (int s = 0; s < 5; ++s) sz[s] = (size_t)N * Ws[s] * Ws[s] * C;

    // Workspace (ushort units): AF table, IMG CX (pad4), L0..L3 CX (pad8).
    unsigned short* wsu = (unsigned short*)d_ws;
    unsigned short* AF  = wsu;                       // 53*64*8 -> pad to 32768
    unsigned short* IMG = AF + 32768;
    unsigned short* L0 = IMG + (size_t)N * 264 * 16 * 264;
    unsigned short* L1 = L0 + (size_t)N * 272 * 16 * 272;
    unsigned short* L2 = L1 + (size_t)N * 144 * 16 * 144;
    unsigned short* L3 = L2 + (size_t)N * 80 * 16 * 80;

    // Output layout (reversed pyramid, flat):
    // [ lo_final | s=3 b=3..0 | s=2 b=3..0 | s=1 b=3..0 | s=0 b=3..0 | hi0 ]
    float* out_lofinal = out;
    size_t o = sz[4];
    float* band_ptr[4][4];
    for (int s = 3; s >= 0; --s)
        for (int b = 3; b >= 0; --b) { band_ptr[s][b] = out + o; o += sz[s]; }
    float* out_hi0 = out + o;

    prep_all<<<3150, 256, 0, stream>>>(
        bfilts, hi0filt, lo0filt, lofilt, AF, L0, L1, L2, L3,
        (const float4*)image, IMG);
    dual_mfma32<<<1024, 256, 0, stream>>>(IMG, out_hi0, L0, AF);
    scale_comb<8, false><<<8 * (256 + 64), 256, 0, stream>>>(
        L0, band_ptr[0][0], band_ptr[0][1], band_ptr[0][2], band_ptr[0][3],
        (void*)L1, AF);
    scale_comb<7, false><<<8 * (64 + 16), 256, 0, stream>>>(
        L1, band_ptr[1][0], band_ptr[1][1], band_ptr[1][2], band_ptr[1][3],
        (void*)L2, AF);
    scale_comb<6, false><<<8 * (16 + 4), 256, 0, stream>>>(
        L2, band_ptr[2][0], band_ptr[2][1], band_ptr[2][2], band_ptr[2][3],
        (void*)L3, AF);
    scale_comb<5, true><<<8 * (4 + 1), 256, 0, stream>>>(
        L3, band_ptr[3][0], band_ptr[3][1], band_ptr[3][2], band_ptr[3][3],
        (void*)out_lofinal, AF);
}

// Round 17
// 135.159 us; speedup vs baseline: 1.3788x; 1.3788x over previous
//
#include <hip/hip_runtime.h>

// Steerable pyramid via MFMA, fp32 I/O, bf16 compute (threshold = 2% of
// per-output absmax; bf16 error 16384 << 46202, verified r12-r16).
// CX layout for staged images: [n][y][c 16][x] bf16, zero-padded.
// Core (r15, byte-identical here): 9-tap convs on mfma_f32_32x32x16_bf16
// with fused M (bands: 4 bands x 8 px; dual: 2 rows x 2 filters x 8 px;
// K=16 window), down17 on 16x16x32 k-split.
// D map: col=l&31, row=(reg&3)+8(reg>>2)+4(l>>5).
// r17: ONLY safe launch fusion: prep_all (memory ops) + tail scale_comb<6,5>
// (tiny grids). NO __launch_bounds__ min-waves clamps on hot kernels
// (r16's (256,4) clamp shrank the B-prefetch window -> +31 us).

typedef __attribute__((ext_vector_type(8))) short short8v;
typedef __attribute__((ext_vector_type(4))) float f32x4;
typedef __attribute__((ext_vector_type(16))) float f32x16;

static __device__ __forceinline__ unsigned short f2bf(float f) {
    union { float f; unsigned u; } v; v.f = f;
    unsigned u = v.u;
    u += 0x7fffu + ((u >> 16) & 1u);
    return (unsigned short)(u >> 16);
}

static __device__ __forceinline__ unsigned pack2(float a, float b) {
    return (unsigned)f2bf(a) | ((unsigned)f2bf(b) << 16);
}

static __device__ __forceinline__ void nt_storef(float* p, float v) {
    __builtin_nontemporal_store(v, p);
}

// AF fragment table rows (entry = short8v per lane, row*64+l):
// [0..8] bands32 dy | [9..18] dual32 i | [19..35] down A1 | [36..52] down A2

// ---------------------------------------------------------------- prep

static __device__ __forceinline__ void do_build_frags(
    const float* bf, const float* fh, const float* fl, const float* lfilt,
    unsigned short* AF, int id)
{
    if (id >= 53 * 64) return;
    int row = id >> 6, l = id & 63;
    short8v a;
    if (row < 9) {
        int dy = row;
        int m = l & 31, f = m >> 3, p = m & 7, kb = (l >> 5) * 8;
        #pragma unroll
        for (int i = 0; i < 8; ++i) {
            int d = kb + i - p;
            a[i] = (short)((d >= 0 && d < 9) ? f2bf(bf[f * 81 + dy * 9 + d]) : 0);
        }
    } else if (row < 19) {
        int is = row - 9;
        int m = l & 31, ry = m >> 4, f = (m >> 3) & 1, p = m & 7, kb = (l >> 5) * 8;
        int dy = is - ry;
        const float* fr = f ? fl : fh;
        #pragma unroll
        for (int i = 0; i < 8; ++i) {
            int dx = kb + i - p;
            bool ok = (dy >= 0 && dy < 9) && (dx >= 0 && dx < 9);
            a[i] = (short)(ok ? f2bf(fr[dy * 9 + dx]) : 0);
        }
    } else if (row < 36) {
        int dy = row - 19;
        int m = l & 15, kb = (l >> 4) * 8;
        #pragma unroll
        for (int i = 0; i < 8; ++i) {
            int d = kb + i - 2 * m;
            a[i] = (short)((d >= 0 && d < 17) ? f2bf(lfilt[dy * 17 + d]) : 0);
        }
    } else {
        int dy = row - 36;
        int m = l & 15, kb = (l >> 4) * 8;
        #pragma unroll
        for (int i = 0; i < 8; ++i) {
            int d = 32 + kb + i - 2 * m;
            a[i] = (short)((d >= 0 && d < 17) ? f2bf(lfilt[dy * 17 + d]) : 0);
        }
    }
    *(short8v*)(AF + (size_t)id * 8) = a;
}

static __device__ __forceinline__ void zero_cx_vec(
    unsigned short* buf, int W, int id)
{
    int Wp = W + 16, Wv = Wp >> 3;
    int rowT = 16 * 16 * Wv;
    int perN = rowT + W * 32;
    int n = id / perN;
    int r = id - n * perN;
    int y, c, xv;
    if (r < rowT) {
        int ry = r / (16 * Wv);
        int rem = r - ry * (16 * Wv);
        c = rem / Wv;
        xv = rem - c * Wv;
        y = (ry < 8) ? ry : ry + W;
    } else {
        int r2 = r - rowT;
        y = 8 + (r2 >> 5);
        int rem = r2 & 31;
        c = rem >> 1;
        xv = (rem & 1) ? (Wv - 1) : 0;
    }
    short8v z = {0, 0, 0, 0, 0, 0, 0, 0};
    *(short8v*)(buf + ((size_t)(n * Wp + y) * 16 + c) * Wp + xv * 8) = z;
}

// prep_all: [0,14) build_frags | [14,1038) zero_pads | [1038,3150) img_to_cx.
__global__ __launch_bounds__(256) void prep_all(
    const float* __restrict__ bf, const float* __restrict__ fh,
    const float* __restrict__ fl, const float* __restrict__ lfilt,
    unsigned short* __restrict__ AF,
    unsigned short* __restrict__ L0, unsigned short* __restrict__ L1,
    unsigned short* __restrict__ L2, unsigned short* __restrict__ L3,
    const float4* __restrict__ src4, unsigned short* __restrict__ IMG)
{
    __shared__ unsigned short lds[16][264];
    int b = blockIdx.x, t = threadIdx.x;
    if (b < 14) {
        do_build_frags(bf, fh, fl, lfilt, AF, b * 256 + t);
    } else if (b < 1038) {
        int zb = b - 14;
        if (zb < 528)      zero_cx_vec(L0, 256, zb * 256 + t);
        else if (zb < 800) zero_cx_vec(L1, 128, (zb - 528) * 256 + t);
        else if (zb < 944) zero_cx_vec(L2, 64,  (zb - 800) * 256 + t);
        else               zero_cx_vec(L3, 32,  (zb - 944) * 256 + t);
    } else {
        int ib = b - 1038;                   // 2112 = 8 * 264
        int n = ib & 7;
        int yp = ib >> 3;
        int y = yp - 4;
        unsigned short* drow = IMG + ((size_t)(n * 264 + yp) * 16) * 264;
        if ((unsigned)y < 256u) {
            for (int task = t; task < 1056; task += 256) {
                int px = task >> 2, cg = task & 3;
                int xs = px - 4;
                bool ok = (unsigned)xs < 256u;
                int xc = min(max(xs, 0), 255);
                float4 v = src4[((size_t)(n * 256 + y) * 256 + xc) * 4 + cg];
                lds[cg * 4 + 0][px] = (unsigned short)(ok ? f2bf(v.x) : 0);
                lds[cg * 4 + 1][px] = (unsigned short)(ok ? f2bf(v.y) : 0);
                lds[cg * 4 + 2][px] = (unsigned short)(ok ? f2bf(v.z) : 0);
                lds[cg * 4 + 3][px] = (unsigned short)(ok ? f2bf(v.w) : 0);
            }
            __syncthreads();
            for (int task = t; task < 528; task += 256) {
                int c = task / 33, xg = task - c * 33;
                short8v v = *(const short8v*)&lds[c][xg * 8];
                *(short8v*)(drow + (size_t)c * 264 + xg * 8) = v;
            }
        } else {
            short8v z = {0, 0, 0, 0, 0, 0, 0, 0};
            for (int task = t; task < 528; task += 256) {
                int c = task / 33, xg = task - c * 33;
                *(short8v*)(drow + (size_t)c * 264 + xg * 8) = z;
            }
        }
    }
}

// ---------------------------------------------------------------- MFMA convs

#define MFMA16 __builtin_amdgcn_mfma_f32_16x16x32_bf16
#define MFMA32 __builtin_amdgcn_mfma_f32_32x32x16_bf16

// hi0 + lo0 from IMG CX (pad 4), 32x32x16, M = 2 rows x 2 filt x 8 px.
__global__ __launch_bounds__(256) void dual_mfma32(
    const unsigned short* __restrict__ img,
    float* __restrict__ hi0, unsigned short* __restrict__ lo0,
    const unsigned short* __restrict__ AF)
{
    const int RS = 16 * 264;
    int n = blockIdx.x & 7;
    int q = blockIdx.x >> 3;
    int xseg = q & 15, yq = q >> 4;
    int t = threadIdx.x, wv = t >> 6, l = t & 63;
    int j = l & 31, pg = j >> 4, c = j & 15, kb = (l >> 5) * 8, hi = l >> 5;
    int x0 = xseg * 16;
    int pbase = (yq * 4 + wv) * 4;

    short8v A[10];
    #pragma unroll
    for (int i = 0; i < 10; ++i)
        A[i] = *(const short8v*)(AF + ((size_t)((9 + i) * 64 + l)) * 8);

    #pragma unroll 1
    for (int tp = 0; tp < 4; ++tp) {
        int y = (pbase + tp) * 2;
        const unsigned short* base =
            img + ((size_t)(n * 264 + y) * 16 + c) * 264 + x0 + pg * 8 + kb;
        f32x16 acc = {};
        #pragma unroll
        for (int i = 0; i < 10; ++i) {
            short8v B = *(const short8v*)(base + (size_t)i * RS);
            acc = MFMA32(A[i], B, acc, 0, 0, 0);
        }
        #pragma unroll
        for (int ry = 0; ry < 2; ++ry) {
            size_t hb = ((size_t)(n * 256 + y + ry) * 256 + x0 + pg * 8) * 16 + c;
            #pragma unroll
            for (int rr = 0; rr < 4; ++rr) {
                int r = ry * 8 + rr;
                int p = rr + 4 * hi;
                nt_storef(hi0 + hb + (size_t)p * 16, acc[r]);
            }
            size_t lb = ((size_t)(n * 272 + y + ry + 8) * 16 + c) * 272
                        + (x0 + pg * 8 + 4 * hi + 8);
            int r0 = ry * 8 + 4;
            *(unsigned*)(lo0 + lb)     = pack2(acc[r0],     acc[r0 + 1]);
            *(unsigned*)(lo0 + lb + 2) = pack2(acc[r0 + 2], acc[r0 + 3]);
        }
    }
}

// 4 band convs, 32x32x16, M = 4 bands x 8 px. One MFMA per dy.
template <int LOGW>
__global__ __launch_bounds__(256) void bands_mfma32(
    const unsigned short* __restrict__ in,
    float* __restrict__ b0, float* __restrict__ b1,
    float* __restrict__ b2, float* __restrict__ b3,
    const unsigned short* __restrict__ AF)
{
    const int W = 1 << LOGW, Wp = W + 16, XS = W / 16, RS = 16 * Wp;
    int n = blockIdx.x & 7;
    int q = blockIdx.x >> 3;
    int xseg = q & (XS - 1), yq = q >> (LOGW - 4);
    int t = threadIdx.x, wv = t >> 6, l = t & 63;
    int j = l & 31, pg = j >> 4, c = j & 15, kb = (l >> 5) * 8, hi = l >> 5;
    int x0 = xseg * 16;
    int ybase = (yq * 4 + wv) * 4;

    short8v A[9];
    #pragma unroll
    for (int dy = 0; dy < 9; ++dy)
        A[dy] = *(const short8v*)(AF + ((size_t)(dy * 64 + l)) * 8);

    #pragma unroll 1
    for (int ty = 0; ty < 4; ++ty) {
        int y = ybase + ty;
        const unsigned short* base =
            in + ((size_t)(n * Wp + y + 4) * 16 + c) * Wp + x0 + pg * 8 + kb + 4;
        f32x16 acc = {};
        #pragma unroll
        for (int dy = 0; dy < 9; ++dy) {
            short8v B = *(const short8v*)(base + (size_t)dy * RS);
            acc = MFMA32(A[dy], B, acc, 0, 0, 0);
        }
        size_t ob = ((size_t)(n * W + y) * W + x0 + pg * 8) * 16 + c;
        #pragma unroll
        for (int rr = 0; rr < 4; ++rr) {
            size_t o = ob + (size_t)(rr + 4 * hi) * 16;
            nt_storef(b0 + o, acc[rr]);
            nt_storef(b1 + o, acc[4 + rr]);
            nt_storef(b2 + o, acc[8 + rr]);
            nt_storef(b3 + o, acc[12 + rr]);
        }
    }
}

// 17x17 stride-2 downsample (16x16x32, k-split), A preloaded (r15 form).
template <int LOGW, bool OUTF32>
__global__ __launch_bounds__(256) void down_mfma(
    const unsigned short* __restrict__ in, void* __restrict__ outp,
    const unsigned short* __restrict__ AF)
{
    const int W = 1 << LOGW, Wpi = W + 16, Wo = W >> 1, Wpo = Wo + 16;
    const int XS = Wo / 16, RS = 16 * Wpi;
    int n = blockIdx.x & 7;
    int q = blockIdx.x >> 3;
    int xseg = q & (XS - 1), yq = q >> (LOGW - 5);
    int t = threadIdx.x, wv = t >> 6, l = t & 63;
    int m = l & 15, g = l >> 4, kb = g * 8;
    int x0 = xseg * 16;
    int ybase = (yq * 4 + wv) * 4;
    int off2 = (g < 2) ? 32 : 0;

    short8v A1[17], A2[17];
    #pragma unroll
    for (int dy = 0; dy < 17; ++dy) {
        A1[dy] = *(const short8v*)(AF + ((size_t)((19 + dy) * 64 + l)) * 8);
        A2[dy] = *(const short8v*)(AF + ((size_t)((36 + dy) * 64 + l)) * 8);
    }

    #pragma unroll 1
    for (int ty = 0; ty < 4; ++ty) {
        int yo = ybase + ty;
        const unsigned short* base =
            in + ((size_t)(n * Wpi + 2 * yo) * 16 + m) * Wpi + 2 * x0 + kb;
        f32x4 aA = {0, 0, 0, 0}, aB = {0, 0, 0, 0};
        #pragma unroll
        for (int dy = 0; dy < 17; ++dy) {
            short8v B1 = *(const short8v*)(base + (size_t)dy * RS);
            short8v B2 = *(const short8v*)(base + (size_t)dy * RS + off2);
            aA = MFMA16(A1[dy], B1, aA, 0, 0, 0);
            aB = MFMA16(A2[dy], B2, aB, 0, 0, 0);
        }
        f32x4 acc = aA + aB;
        if (OUTF32) {
            float* o = (float*)outp;
            size_t ob = ((size_t)(n * Wo + yo) * Wo + x0 + g * 4) * 16 + m;
            #pragma unroll
            for (int r = 0; r < 4; ++r) nt_storef(o + ob + (size_t)r * 16, acc[r]);
        } else {
            unsigned short* o = (unsigned short*)outp;
            size_t lb = ((size_t)(n * Wpo + yo + 8) * 16 + m) * Wpo + (x0 + 8 + g * 4);
            *(unsigned*)(o + lb)     = pack2(acc[0], acc[1]);
            *(unsigned*)(o + lb + 2) = pack2(acc[2], acc[3]);
        }
    }
}

// Fused tail scale (s=2,3 only; tiny grids): q < bandsPerN -> bands,
// else down17 with A loaded per-dy from the L1-hot AF table. No clamp.
template <int LOGW, bool OUTF32>
__global__ __launch_bounds__(256) void scale_comb(
    const unsigned short* __restrict__ in,
    float* __restrict__ b0, float* __restrict__ b1,
    float* __restrict__ b2, float* __restrict__ b3,
    void* __restrict__ lo_out,
    const unsigned short* __restrict__ AF)
{
    const int W = 1 << LOGW, Wp = W + 16, XS = W / 16, RS = 16 * Wp;
    const int Wo = W >> 1, Wpo = Wo + 16, XS2 = Wo / 16;
    const int bandsPerN = XS * XS;
    int n = blockIdx.x & 7;
    int q = blockIdx.x >> 3;
    int t = threadIdx.x, wv = t >> 6, l = t & 63;

    if (q < bandsPerN) {
        int xseg = q & (XS - 1), yq = q >> (LOGW - 4);
        int j = l & 31, pg = j >> 4, c = j & 15, kb = (l >> 5) * 8, hi = l >> 5;
        int x0 = xseg * 16;
        int ybase = (yq * 4 + wv) * 4;

        short8v A[9];
        #pragma unroll
        for (int dy = 0; dy < 9; ++dy)
            A[dy] = *(const short8v*)(AF + ((size_t)(dy * 64 + l)) * 8);

        #pragma unroll 1
        for (int ty = 0; ty < 4; ++ty) {
            int y = ybase + ty;
            const unsigned short* base =
                in + ((size_t)(n * Wp + y + 4) * 16 + c) * Wp + x0 + pg * 8 + kb + 4;
            f32x16 acc = {};
            #pragma unroll
            for (int dy = 0; dy < 9; ++dy) {
                short8v B = *(const short8v*)(base + (size_t)dy * RS);
                acc = MFMA32(A[dy], B, acc, 0, 0, 0);
            }
            size_t ob = ((size_t)(n * W + y) * W + x0 + pg * 8) * 16 + c;
            #pragma unroll
            for (int rr = 0; rr < 4; ++rr) {
                size_t o = ob + (size_t)(rr + 4 * hi) * 16;
                nt_storef(b0 + o, acc[rr]);
                nt_storef(b1 + o, acc[4 + rr]);
                nt_storef(b2 + o, acc[8 + rr]);
                nt_storef(b3 + o, acc[12 + rr]);
            }
        }
    } else {
        int q2 = q - bandsPerN;
        int xseg = q2 & (XS2 - 1), yq = q2 >> (LOGW - 5);
        int m = l & 15, g = l >> 4, kb = g * 8;
        int x0 = xseg * 16;
        int ybase = (yq * 4 + wv) * 4;
        int off2 = (g < 2) ? 32 : 0;

        #pragma unroll 1
        for (int ty = 0; ty < 4; ++ty) {
            int yo = ybase + ty;
            const unsigned short* base =
                in + ((size_t)(n * Wp + 2 * yo) * 16 + m) * Wp + 2 * x0 + kb;
            f32x4 aA = {0, 0, 0, 0}, aB = {0, 0, 0, 0};
            #pragma unroll
            for (int dy = 0; dy < 17; ++dy) {
                short8v A1 = *(const short8v*)(AF + ((size_t)((19 + dy) * 64 + l)) * 8);
                short8v A2 = *(const short8v*)(AF + ((size_t)((36 + dy) * 64 + l)) * 8);
                short8v B1 = *(const short8v*)(base + (size_t)dy * RS);
                short8v B2 = *(const short8v*)(base + (size_t)dy * RS + off2);
                aA = MFMA16(A1, B1, aA, 0, 0, 0);
                aB = MFMA16(A2, B2, aB, 0, 0, 0);
            }
            f32x4 acc = aA + aB;
            if (OUTF32) {
                float* o = (float*)lo_out;
                size_t ob = ((size_t)(n * Wo + yo) * Wo + x0 + g * 4) * 16 + m;
                #pragma unroll
                for (int r = 0; r < 4; ++r) nt_storef(o + ob + (size_t)r * 16, acc[r]);
            } else {
                unsigned short* o = (unsigned short*)lo_out;
                size_t lb = ((size_t)(n * Wpo + yo + 8) * 16 + m) * Wpo + (x0 + 8 + g * 4);
                *(unsigned*)(o + lb)     = pack2(acc[0], acc[1]);
                *(unsigned*)(o + lb + 2) = pack2(acc[2], acc[3]);
            }
        }
    }
}

// ---------------------------------------------------------------- launch

extern "C" void kernel_launch(void* const* d_in, const int* in_sizes, int n_in,
                              void* d_out, int out_size, void* d_ws, size_t ws_size,
                              hipStream_t stream) {
    const float* image   = (const float*)d_in[0];
    const float* lo0filt = (const float*)d_in[1];
    const float* hi0filt = (const float*)d_in[2];
    const float* lofilt  = (const float*)d_in[3];
    const float* bfilts  = (const float*)d_in[4];
    float* out = (float*)d_out;

    const int N = 8, C = 16;
    size_t sz[5];
    const int Ws[5] = {256, 128, 64, 32, 16};
    for (int s = 0; s < 5; ++s) sz[s] = (size_t)N * Ws[s] * Ws[s] * C;

    // Workspace (ushort units): AF table, IMG CX (pad4), L0..L3 CX (pad8).
    unsigned short* wsu = (unsigned short*)d_ws;
    unsigned short* AF  = wsu;                       // 53*64*8 -> pad to 32768
    unsigned short* IMG = AF + 32768;
    unsigned short* L0 = IMG + (size_t)N * 264 * 16 * 264;
    unsigned short* L1 = L0 + (size_t)N * 272 * 16 * 272;
    unsigned short* L2 = L1 + (size_t)N * 144 * 16 * 144;
    unsigned short* L3 = L2 + (size_t)N * 80 * 16 * 80;

    // Output layout (reversed pyramid, flat):
    // [ lo_final | s=3 b=3..0 | s=2 b=3..0 | s=1 b=3..0 | s=0 b=3..0 | hi0 ]
    float* out_lofinal = out;
    size_t o = sz[4];
    float* band_ptr[4][4];
    for (int s = 3; s >= 0; --s)
        for (int b = 3; b >= 0; --b) { band_ptr[s][b] = out + o; o += sz[s]; }
    float* out_hi0 = out + o;

    prep_all<<<3150, 256, 0, stream>>>(
        bfilts, hi0filt, lo0filt, lofilt, AF, L0, L1, L2, L3,
        (const float4*)image, IMG);
    dual_mfma32<<<1024, 256, 0, stream>>>(IMG, out_hi0, L0, AF);
    down_mfma<8, false><<<512, 256, 0, stream>>>(L0, L1, AF);
    bands_mfma32<8><<<2048, 256, 0, stream>>>(
        L0, band_ptr[0][0], band_ptr[0][1], band_ptr[0][2], band_ptr[0][3], AF);
    down_mfma<7, false><<<128, 256, 0, stream>>>(L1, L2, AF);
    bands_mfma32<7><<<512, 256, 0, stream>>>(
        L1, band_ptr[1][0], band_ptr[1][1], band_ptr[1][2], band_ptr[1][3], AF);
    scale_comb<6, false><<<8 * (16 + 4), 256, 0, stream>>>(
        L2, band_ptr[2][0], band_ptr[2][1], band_ptr[2][2], band_ptr[2][3],
        (void*)L3, AF);
    scale_comb<5, true><<<8 * (4 + 1), 256, 0, stream>>>(
        L3, band_ptr[3][0], band_ptr[3][1], band_ptr[3][2], band_ptr[3][3],
        (void*)out_lofinal, AF);
}

// Round 18
// 128.222 us; speedup vs baseline: 1.4533x; 1.0541x over previous
//
#include <hip/hip_runtime.h>

// Steerable pyramid via MFMA, fp32 I/O, bf16 compute (threshold = 2% of
// per-output absmax; bf16 error 16384 << 46202, verified r12-r17).
// CX layout for staged images: [n][y][c 16][x] bf16, zero-padded.
// Core (r15): 9-tap convs on mfma_f32_32x32x16_bf16 with fused M
// (bands: 4 bands x 8 px; dual: 2 rows x 2 filters x 8 px; K=16 window),
// down17 on 16x16x32 k-split. D map: col=l&31, row=(reg&3)+8(reg>>2)+4(l>>5).
// r17 lesson: NO __launch_bounds__ min-waves clamps on MFMA kernels
// (r16's (256,4) clamp cost +31 us); prep_all + tail fusion are wins.
// r18: clamp-free scale_comb at ALL scales -> 6 launches total:
// prep_all, dual, sc<8>, sc<7>, sc<6>, sc<5>.

typedef __attribute__((ext_vector_type(8))) short short8v;
typedef __attribute__((ext_vector_type(4))) float f32x4;
typedef __attribute__((ext_vector_type(16))) float f32x16;

static __device__ __forceinline__ unsigned short f2bf(float f) {
    union { float f; unsigned u; } v; v.f = f;
    unsigned u = v.u;
    u += 0x7fffu + ((u >> 16) & 1u);
    return (unsigned short)(u >> 16);
}

static __device__ __forceinline__ unsigned pack2(float a, float b) {
    return (unsigned)f2bf(a) | ((unsigned)f2bf(b) << 16);
}

static __device__ __forceinline__ void nt_storef(float* p, float v) {
    __builtin_nontemporal_store(v, p);
}

// AF fragment table rows (entry = short8v per lane, row*64+l):
// [0..8] bands32 dy | [9..18] dual32 i | [19..35] down A1 | [36..52] down A2

// ---------------------------------------------------------------- prep

static __device__ __forceinline__ void do_build_frags(
    const float* bf, const float* fh, const float* fl, const float* lfilt,
    unsigned short* AF, int id)
{
    if (id >= 53 * 64) return;
    int row = id >> 6, l = id & 63;
    short8v a;
    if (row < 9) {
        int dy = row;
        int m = l & 31, f = m >> 3, p = m & 7, kb = (l >> 5) * 8;
        #pragma unroll
        for (int i = 0; i < 8; ++i) {
            int d = kb + i - p;
            a[i] = (short)((d >= 0 && d < 9) ? f2bf(bf[f * 81 + dy * 9 + d]) : 0);
        }
    } else if (row < 19) {
        int is = row - 9;
        int m = l & 31, ry = m >> 4, f = (m >> 3) & 1, p = m & 7, kb = (l >> 5) * 8;
        int dy = is - ry;
        const float* fr = f ? fl : fh;
        #pragma unroll
        for (int i = 0; i < 8; ++i) {
            int dx = kb + i - p;
            bool ok = (dy >= 0 && dy < 9) && (dx >= 0 && dx < 9);
            a[i] = (short)(ok ? f2bf(fr[dy * 9 + dx]) : 0);
        }
    } else if (row < 36) {
        int dy = row - 19;
        int m = l & 15, kb = (l >> 4) * 8;
        #pragma unroll
        for (int i = 0; i < 8; ++i) {
            int d = kb + i - 2 * m;
            a[i] = (short)((d >= 0 && d < 17) ? f2bf(lfilt[dy * 17 + d]) : 0);
        }
    } else {
        int dy = row - 36;
        int m = l & 15, kb = (l >> 4) * 8;
        #pragma unroll
        for (int i = 0; i < 8; ++i) {
            int d = 32 + kb + i - 2 * m;
            a[i] = (short)((d >= 0 && d < 17) ? f2bf(lfilt[dy * 17 + d]) : 0);
        }
    }
    *(short8v*)(AF + (size_t)id * 8) = a;
}

static __device__ __forceinline__ void zero_cx_vec(
    unsigned short* buf, int W, int id)
{
    int Wp = W + 16, Wv = Wp >> 3;
    int rowT = 16 * 16 * Wv;
    int perN = rowT + W * 32;
    int n = id / perN;
    int r = id - n * perN;
    int y, c, xv;
    if (r < rowT) {
        int ry = r / (16 * Wv);
        int rem = r - ry * (16 * Wv);
        c = rem / Wv;
        xv = rem - c * Wv;
        y = (ry < 8) ? ry : ry + W;
    } else {
        int r2 = r - rowT;
        y = 8 + (r2 >> 5);
        int rem = r2 & 31;
        c = rem >> 1;
        xv = (rem & 1) ? (Wv - 1) : 0;
    }
    short8v z = {0, 0, 0, 0, 0, 0, 0, 0};
    *(short8v*)(buf + ((size_t)(n * Wp + y) * 16 + c) * Wp + xv * 8) = z;
}

// prep_all: [0,14) build_frags | [14,1038) zero_pads | [1038,3150) img_to_cx.
__global__ __launch_bounds__(256) void prep_all(
    const float* __restrict__ bf, const float* __restrict__ fh,
    const float* __restrict__ fl, const float* __restrict__ lfilt,
    unsigned short* __restrict__ AF,
    unsigned short* __restrict__ L0, unsigned short* __restrict__ L1,
    unsigned short* __restrict__ L2, unsigned short* __restrict__ L3,
    const float4* __restrict__ src4, unsigned short* __restrict__ IMG)
{
    __shared__ unsigned short lds[16][264];
    int b = blockIdx.x, t = threadIdx.x;
    if (b < 14) {
        do_build_frags(bf, fh, fl, lfilt, AF, b * 256 + t);
    } else if (b < 1038) {
        int zb = b - 14;
        if (zb < 528)      zero_cx_vec(L0, 256, zb * 256 + t);
        else if (zb < 800) zero_cx_vec(L1, 128, (zb - 528) * 256 + t);
        else if (zb < 944) zero_cx_vec(L2, 64,  (zb - 800) * 256 + t);
        else               zero_cx_vec(L3, 32,  (zb - 944) * 256 + t);
    } else {
        int ib = b - 1038;                   // 2112 = 8 * 264
        int n = ib & 7;
        int yp = ib >> 3;
        int y = yp - 4;
        unsigned short* drow = IMG + ((size_t)(n * 264 + yp) * 16) * 264;
        if ((unsigned)y < 256u) {
            for (int task = t; task < 1056; task += 256) {
                int px = task >> 2, cg = task & 3;
                int xs = px - 4;
                bool ok = (unsigned)xs < 256u;
                int xc = min(max(xs, 0), 255);
                float4 v = src4[((size_t)(n * 256 + y) * 256 + xc) * 4 + cg];
                lds[cg * 4 + 0][px] = (unsigned short)(ok ? f2bf(v.x) : 0);
                lds[cg * 4 + 1][px] = (unsigned short)(ok ? f2bf(v.y) : 0);
                lds[cg * 4 + 2][px] = (unsigned short)(ok ? f2bf(v.z) : 0);
                lds[cg * 4 + 3][px] = (unsigned short)(ok ? f2bf(v.w) : 0);
            }
            __syncthreads();
            for (int task = t; task < 528; task += 256) {
                int c = task / 33, xg = task - c * 33;
                short8v v = *(const short8v*)&lds[c][xg * 8];
                *(short8v*)(drow + (size_t)c * 264 + xg * 8) = v;
            }
        } else {
            short8v z = {0, 0, 0, 0, 0, 0, 0, 0};
            for (int task = t; task < 528; task += 256) {
                int c = task / 33, xg = task - c * 33;
                *(short8v*)(drow + (size_t)c * 264 + xg * 8) = z;
            }
        }
    }
}

// ---------------------------------------------------------------- MFMA convs

#define MFMA16 __builtin_amdgcn_mfma_f32_16x16x32_bf16
#define MFMA32 __builtin_amdgcn_mfma_f32_32x32x16_bf16

// hi0 + lo0 from IMG CX (pad 4), 32x32x16, M = 2 rows x 2 filt x 8 px.
__global__ __launch_bounds__(256) void dual_mfma32(
    const unsigned short* __restrict__ img,
    float* __restrict__ hi0, unsigned short* __restrict__ lo0,
    const unsigned short* __restrict__ AF)
{
    const int RS = 16 * 264;
    int n = blockIdx.x & 7;
    int q = blockIdx.x >> 3;
    int xseg = q & 15, yq = q >> 4;
    int t = threadIdx.x, wv = t >> 6, l = t & 63;
    int j = l & 31, pg = j >> 4, c = j & 15, kb = (l >> 5) * 8, hi = l >> 5;
    int x0 = xseg * 16;
    int pbase = (yq * 4 + wv) * 4;

    short8v A[10];
    #pragma unroll
    for (int i = 0; i < 10; ++i)
        A[i] = *(const short8v*)(AF + ((size_t)((9 + i) * 64 + l)) * 8);

    #pragma unroll 1
    for (int tp = 0; tp < 4; ++tp) {
        int y = (pbase + tp) * 2;
        const unsigned short* base =
            img + ((size_t)(n * 264 + y) * 16 + c) * 264 + x0 + pg * 8 + kb;
        f32x16 acc = {};
        #pragma unroll
        for (int i = 0; i < 10; ++i) {
            short8v B = *(const short8v*)(base + (size_t)i * RS);
            acc = MFMA32(A[i], B, acc, 0, 0, 0);
        }
        #pragma unroll
        for (int ry = 0; ry < 2; ++ry) {
            size_t hb = ((size_t)(n * 256 + y + ry) * 256 + x0 + pg * 8) * 16 + c;
            #pragma unroll
            for (int rr = 0; rr < 4; ++rr) {
                int r = ry * 8 + rr;
                int p = rr + 4 * hi;
                nt_storef(hi0 + hb + (size_t)p * 16, acc[r]);
            }
            size_t lb = ((size_t)(n * 272 + y + ry + 8) * 16 + c) * 272
                        + (x0 + pg * 8 + 4 * hi + 8);
            int r0 = ry * 8 + 4;
            *(unsigned*)(lo0 + lb)     = pack2(acc[r0],     acc[r0 + 1]);
            *(unsigned*)(lo0 + lb + 2) = pack2(acc[r0 + 2], acc[r0 + 3]);
        }
    }
}

// Fused per-scale (clamp-free): q < bandsPerN -> bands (32x32x16, A
// preloaded); else down17 (16x16x32, A loaded per-dy from L1-hot AF).
template <int LOGW, bool OUTF32>
__global__ __launch_bounds__(256) void scale_comb(
    const unsigned short* __restrict__ in,
    float* __restrict__ b0, float* __restrict__ b1,
    float* __restrict__ b2, float* __restrict__ b3,
    void* __restrict__ lo_out,
    const unsigned short* __restrict__ AF)
{
    const int W = 1 << LOGW, Wp = W + 16, XS = W / 16, RS = 16 * Wp;
    const int Wo = W >> 1, Wpo = Wo + 16, XS2 = Wo / 16;
    const int bandsPerN = XS * XS;
    int n = blockIdx.x & 7;
    int q = blockIdx.x >> 3;
    int t = threadIdx.x, wv = t >> 6, l = t & 63;

    if (q < bandsPerN) {
        int xseg = q & (XS - 1), yq = q >> (LOGW - 4);
        int j = l & 31, pg = j >> 4, c = j & 15, kb = (l >> 5) * 8, hi = l >> 5;
        int x0 = xseg * 16;
        int ybase = (yq * 4 + wv) * 4;

        short8v A[9];
        #pragma unroll
        for (int dy = 0; dy < 9; ++dy)
            A[dy] = *(const short8v*)(AF + ((size_t)(dy * 64 + l)) * 8);

        #pragma unroll 1
        for (int ty = 0; ty < 4; ++ty) {
            int y = ybase + ty;
            const unsigned short* base =
                in + ((size_t)(n * Wp + y + 4) * 16 + c) * Wp + x0 + pg * 8 + kb + 4;
            f32x16 acc = {};
            #pragma unroll
            for (int dy = 0; dy < 9; ++dy) {
                short8v B = *(const short8v*)(base + (size_t)dy * RS);
                acc = MFMA32(A[dy], B, acc, 0, 0, 0);
            }
            size_t ob = ((size_t)(n * W + y) * W + x0 + pg * 8) * 16 + c;
            #pragma unroll
            for (int rr = 0; rr < 4; ++rr) {
                size_t o = ob + (size_t)(rr + 4 * hi) * 16;
                nt_storef(b0 + o, acc[rr]);
                nt_storef(b1 + o, acc[4 + rr]);
                nt_storef(b2 + o, acc[8 + rr]);
                nt_storef(b3 + o, acc[12 + rr]);
            }
        }
    } else {
        int q2 = q - bandsPerN;
        int xseg = q2 & (XS2 - 1), yq = q2 >> (LOGW - 5);
        int m = l & 15, g = l >> 4, kb = g * 8;
        int x0 = xseg * 16;
        int ybase = (yq * 4 + wv) * 4;
        int off2 = (g < 2) ? 32 : 0;

        #pragma unroll 1
        for (int ty = 0; ty < 4; ++ty) {
            int yo = ybase + ty;
            const unsigned short* base =
                in + ((size_t)(n * Wp + 2 * yo) * 16 + m) * Wp + 2 * x0 + kb;
            f32x4 aA = {0, 0, 0, 0}, aB = {0, 0, 0, 0};
            #pragma unroll
            for (int dy = 0; dy < 17; ++dy) {
                short8v A1 = *(const short8v*)(AF + ((size_t)((19 + dy) * 64 + l)) * 8);
                short8v A2 = *(const short8v*)(AF + ((size_t)((36 + dy) * 64 + l)) * 8);
                short8v B1 = *(const short8v*)(base + (size_t)dy * RS);
                short8v B2 = *(const short8v*)(base + (size_t)dy * RS + off2);
                aA = MFMA16(A1, B1, aA, 0, 0, 0);
                aB = MFMA16(A2, B2, aB, 0, 0, 0);
            }
            f32x4 acc = aA + aB;
            if (OUTF32) {
                float* o = (float*)lo_out;
                size_t ob = ((size_t)(n * Wo + yo) * Wo + x0 + g * 4) * 16 + m;
                #pragma unroll
                for (int r = 0; r < 4; ++r) nt_storef(o + ob + (size_t)r * 16, acc[r]);
            } else {
                unsigned short* o = (unsigned short*)lo_out;
                size_t lb = ((size_t)(n * Wpo + yo + 8) * 16 + m) * Wpo + (x0 + 8 + g * 4);
                *(unsigned*)(o + lb)     = pack2(acc[0], acc[1]);
                *(unsigned*)(o + lb + 2) = pack2(acc[2], acc[3]);
            }
        }
    }
}

// ---------------------------------------------------------------- launch

extern "C" void kernel_launch(void* const* d_in, const int* in_sizes, int n_in,
                              void* d_out, int out_size, void* d_ws, size_t ws_size,
                              hipStream_t stream) {
    const float* image   = (const float*)d_in[0];
    const float* lo0filt = (const float*)d_in[1];
    const float* hi0filt = (const float*)d_in[2];
    const float* lofilt  = (const float*)d_in[3];
    const float* bfilts  = (const float*)d_in[4];
    float* out = (float*)d_out;

    const int N = 8, C = 16;
    size_t sz[5];
    const int Ws[5] = {256, 128, 64, 32, 16};
    for (int s = 0; s < 5; ++s) sz[s] = (size_t)N * Ws[s] * Ws[s] * C;

    // Workspace (ushort units): AF table, IMG CX (pad4), L0..L3 CX (pad8).
    unsigned short* wsu = (unsigned short*)d_ws;
    unsigned short* AF  = wsu;                       // 53*64*8 -> pad to 32768
    unsigned short* IMG = AF + 32768;
    unsigned short* L0 = IMG + (size_t)N * 264 * 16 * 264;
    unsigned short* L1 = L0 + (size_t)N * 272 * 16 * 272;
    unsigned short* L2 = L1 + (size_t)N * 144 * 16 * 144;
    unsigned short* L3 = L2 + (size_t)N * 80 * 16 * 80;

    // Output layout (reversed pyramid, flat):
    // [ lo_final | s=3 b=3..0 | s=2 b=3..0 | s=1 b=3..0 | s=0 b=3..0 | hi0 ]
    float* out_lofinal = out;
    size_t o = sz[4];
    float* band_ptr[4][4];
    for (int s = 3; s >= 0; --s)
        for (int b = 3; b >= 0; --b) { band_ptr[s][b] = out + o; o += sz[s]; }
    float* out_hi0 = out + o;

    prep_all<<<3150, 256, 0, stream>>>(
        bfilts, hi0filt, lo0filt, lofilt, AF, L0, L1, L2, L3,
        (const float4*)image, IMG);
    dual_mfma32<<<1024, 256, 0, stream>>>(IMG, out_hi0, L0, AF);
    scale_comb<8, false><<<8 * (256 + 64), 256, 0, stream>>>(
        L0, band_ptr[0][0], band_ptr[0][1], band_ptr[0][2], band_ptr[0][3],
        (void*)L1, AF);
    scale_comb<7, false><<<8 * (64 + 16), 256, 0, stream>>>(
        L1, band_ptr[1][0], band_ptr[1][1], band_ptr[1][2], band_ptr[1][3],
        (void*)L2, AF);
    scale_comb<6, false><<<8 * (16 + 4), 256, 0, stream>>>(
        L2, band_ptr[2][0], band_ptr[2][1], band_ptr[2][2], band_ptr[2][3],
        (void*)L3, AF);
    scale_comb<5, true><<<8 * (4 + 1), 256, 0, stream>>>(
        L3, band_ptr[3][0], band_ptr[3][1], band_ptr[3][2], band_ptr[3][3],
        (void*)out_lofinal, AF);
}

// Round 19
// 125.114 us; speedup vs baseline: 1.4895x; 1.0248x over previous
//
#include <hip/hip_runtime.h>

// Steerable pyramid via MFMA, fp32 I/O, bf16 compute (threshold = 2% of
// per-output absmax; bf16 error 16384 << 46202, verified r12-r18).
// CX layout for staged images: [n][y][c 16][x] bf16, zero-padded.
// Core (r15): 9-tap convs on mfma_f32_32x32x16_bf16 with fused M
// (bands: 4 bands x 8 px; dual: 2 rows x 2 filters x 8 px; K=16 window),
// down17 on 16x16x32 k-split. D map: col=l&31, row=(reg&3)+8(reg>>2)+4(l>>5).
// r17/r18 lessons: no __launch_bounds__ min-waves clamps; clamp-free
// scale_comb fusion at all scales (6 launches).
// r19: tiles-per-wave 4 -> 2 in all MFMA kernels (grid x2): dual 2048
// blocks, sc<8> 5120 -- deeper wave pool to hide L2 B-load latency.

typedef __attribute__((ext_vector_type(8))) short short8v;
typedef __attribute__((ext_vector_type(4))) float f32x4;
typedef __attribute__((ext_vector_type(16))) float f32x16;

static __device__ __forceinline__ unsigned short f2bf(float f) {
    union { float f; unsigned u; } v; v.f = f;
    unsigned u = v.u;
    u += 0x7fffu + ((u >> 16) & 1u);
    return (unsigned short)(u >> 16);
}

static __device__ __forceinline__ unsigned pack2(float a, float b) {
    return (unsigned)f2bf(a) | ((unsigned)f2bf(b) << 16);
}

static __device__ __forceinline__ void nt_storef(float* p, float v) {
    __builtin_nontemporal_store(v, p);
}

// AF fragment table rows (entry = short8v per lane, row*64+l):
// [0..8] bands32 dy | [9..18] dual32 i | [19..35] down A1 | [36..52] down A2

// ---------------------------------------------------------------- prep

static __device__ __forceinline__ void do_build_frags(
    const float* bf, const float* fh, const float* fl, const float* lfilt,
    unsigned short* AF, int id)
{
    if (id >= 53 * 64) return;
    int row = id >> 6, l = id & 63;
    short8v a;
    if (row < 9) {
        int dy = row;
        int m = l & 31, f = m >> 3, p = m & 7, kb = (l >> 5) * 8;
        #pragma unroll
        for (int i = 0; i < 8; ++i) {
            int d = kb + i - p;
            a[i] = (short)((d >= 0 && d < 9) ? f2bf(bf[f * 81 + dy * 9 + d]) : 0);
        }
    } else if (row < 19) {
        int is = row - 9;
        int m = l & 31, ry = m >> 4, f = (m >> 3) & 1, p = m & 7, kb = (l >> 5) * 8;
        int dy = is - ry;
        const float* fr = f ? fl : fh;
        #pragma unroll
        for (int i = 0; i < 8; ++i) {
            int dx = kb + i - p;
            bool ok = (dy >= 0 && dy < 9) && (dx >= 0 && dx < 9);
            a[i] = (short)(ok ? f2bf(fr[dy * 9 + dx]) : 0);
        }
    } else if (row < 36) {
        int dy = row - 19;
        int m = l & 15, kb = (l >> 4) * 8;
        #pragma unroll
        for (int i = 0; i < 8; ++i) {
            int d = kb + i - 2 * m;
            a[i] = (short)((d >= 0 && d < 17) ? f2bf(lfilt[dy * 17 + d]) : 0);
        }
    } else {
        int dy = row - 36;
        int m = l & 15, kb = (l >> 4) * 8;
        #pragma unroll
        for (int i = 0; i < 8; ++i) {
            int d = 32 + kb + i - 2 * m;
            a[i] = (short)((d >= 0 && d < 17) ? f2bf(lfilt[dy * 17 + d]) : 0);
        }
    }
    *(short8v*)(AF + (size_t)id * 8) = a;
}

static __device__ __forceinline__ void zero_cx_vec(
    unsigned short* buf, int W, int id)
{
    int Wp = W + 16, Wv = Wp >> 3;
    int rowT = 16 * 16 * Wv;
    int perN = rowT + W * 32;
    int n = id / perN;
    int r = id - n * perN;
    int y, c, xv;
    if (r < rowT) {
        int ry = r / (16 * Wv);
        int rem = r - ry * (16 * Wv);
        c = rem / Wv;
        xv = rem - c * Wv;
        y = (ry < 8) ? ry : ry + W;
    } else {
        int r2 = r - rowT;
        y = 8 + (r2 >> 5);
        int rem = r2 & 31;
        c = rem >> 1;
        xv = (rem & 1) ? (Wv - 1) : 0;
    }
    short8v z = {0, 0, 0, 0, 0, 0, 0, 0};
    *(short8v*)(buf + ((size_t)(n * Wp + y) * 16 + c) * Wp + xv * 8) = z;
}

// prep_all: [0,14) build_frags | [14,1038) zero_pads | [1038,3150) img_to_cx.
__global__ __launch_bounds__(256) void prep_all(
    const float* __restrict__ bf, const float* __restrict__ fh,
    const float* __restrict__ fl, const float* __restrict__ lfilt,
    unsigned short* __restrict__ AF,
    unsigned short* __restrict__ L0, unsigned short* __restrict__ L1,
    unsigned short* __restrict__ L2, unsigned short* __restrict__ L3,
    const float4* __restrict__ src4, unsigned short* __restrict__ IMG)
{
    __shared__ unsigned short lds[16][264];
    int b = blockIdx.x, t = threadIdx.x;
    if (b < 14) {
        do_build_frags(bf, fh, fl, lfilt, AF, b * 256 + t);
    } else if (b < 1038) {
        int zb = b - 14;
        if (zb < 528)      zero_cx_vec(L0, 256, zb * 256 + t);
        else if (zb < 800) zero_cx_vec(L1, 128, (zb - 528) * 256 + t);
        else if (zb < 944) zero_cx_vec(L2, 64,  (zb - 800) * 256 + t);
        else               zero_cx_vec(L3, 32,  (zb - 944) * 256 + t);
    } else {
        int ib = b - 1038;                   // 2112 = 8 * 264
        int n = ib & 7;
        int yp = ib >> 3;
        int y = yp - 4;
        unsigned short* drow = IMG + ((size_t)(n * 264 + yp) * 16) * 264;
        if ((unsigned)y < 256u) {
            for (int task = t; task < 1056; task += 256) {
                int px = task >> 2, cg = task & 3;
                int xs = px - 4;
                bool ok = (unsigned)xs < 256u;
                int xc = min(max(xs, 0), 255);
                float4 v = src4[((size_t)(n * 256 + y) * 256 + xc) * 4 + cg];
                lds[cg * 4 + 0][px] = (unsigned short)(ok ? f2bf(v.x) : 0);
                lds[cg * 4 + 1][px] = (unsigned short)(ok ? f2bf(v.y) : 0);
                lds[cg * 4 + 2][px] = (unsigned short)(ok ? f2bf(v.z) : 0);
                lds[cg * 4 + 3][px] = (unsigned short)(ok ? f2bf(v.w) : 0);
            }
            __syncthreads();
            for (int task = t; task < 528; task += 256) {
                int c = task / 33, xg = task - c * 33;
                short8v v = *(const short8v*)&lds[c][xg * 8];
                *(short8v*)(drow + (size_t)c * 264 + xg * 8) = v;
            }
        } else {
            short8v z = {0, 0, 0, 0, 0, 0, 0, 0};
            for (int task = t; task < 528; task += 256) {
                int c = task / 33, xg = task - c * 33;
                *(short8v*)(drow + (size_t)c * 264 + xg * 8) = z;
            }
        }
    }
}

// ---------------------------------------------------------------- MFMA convs

#define MFMA16 __builtin_amdgcn_mfma_f32_16x16x32_bf16
#define MFMA32 __builtin_amdgcn_mfma_f32_32x32x16_bf16

// hi0 + lo0 from IMG CX (pad 4), 32x32x16, M = 2 rows x 2 filt x 8 px.
// grid 2048: n=b&7, q=b>>3 (256/img): xseg=q&15, yq=q>>4 in [0,16).
// 2 y-pair tiles per wave.
__global__ __launch_bounds__(256) void dual_mfma32(
    const unsigned short* __restrict__ img,
    float* __restrict__ hi0, unsigned short* __restrict__ lo0,
    const unsigned short* __restrict__ AF)
{
    const int RS = 16 * 264;
    int n = blockIdx.x & 7;
    int q = blockIdx.x >> 3;
    int xseg = q & 15, yq = q >> 4;
    int t = threadIdx.x, wv = t >> 6, l = t & 63;
    int j = l & 31, pg = j >> 4, c = j & 15, kb = (l >> 5) * 8, hi = l >> 5;
    int x0 = xseg * 16;
    int pbase = (yq * 4 + wv) * 2;

    short8v A[10];
    #pragma unroll
    for (int i = 0; i < 10; ++i)
        A[i] = *(const short8v*)(AF + ((size_t)((9 + i) * 64 + l)) * 8);

    #pragma unroll 1
    for (int tp = 0; tp < 2; ++tp) {
        int y = (pbase + tp) * 2;
        const unsigned short* base =
            img + ((size_t)(n * 264 + y) * 16 + c) * 264 + x0 + pg * 8 + kb;
        f32x16 acc = {};
        #pragma unroll
        for (int i = 0; i < 10; ++i) {
            short8v B = *(const short8v*)(base + (size_t)i * RS);
            acc = MFMA32(A[i], B, acc, 0, 0, 0);
        }
        #pragma unroll
        for (int ry = 0; ry < 2; ++ry) {
            size_t hb = ((size_t)(n * 256 + y + ry) * 256 + x0 + pg * 8) * 16 + c;
            #pragma unroll
            for (int rr = 0; rr < 4; ++rr) {
                int r = ry * 8 + rr;
                int p = rr + 4 * hi;
                nt_storef(hi0 + hb + (size_t)p * 16, acc[r]);
            }
            size_t lb = ((size_t)(n * 272 + y + ry + 8) * 16 + c) * 272
                        + (x0 + pg * 8 + 4 * hi + 8);
            int r0 = ry * 8 + 4;
            *(unsigned*)(lo0 + lb)     = pack2(acc[r0],     acc[r0 + 1]);
            *(unsigned*)(lo0 + lb + 2) = pack2(acc[r0 + 2], acc[r0 + 3]);
        }
    }
}

// Fused per-scale (clamp-free), 2 tiles/wave:
// q < bandsPerN -> bands (32x32x16, A preloaded);
// else down17 (16x16x32, A loaded per-dy from L1-hot AF).
// bandsPerN = (W/16)*(W/8); downPerN = (Wo/16)*(Wo/8).
template <int LOGW, bool OUTF32>
__global__ __launch_bounds__(256) void scale_comb(
    const unsigned short* __restrict__ in,
    float* __restrict__ b0, float* __restrict__ b1,
    float* __restrict__ b2, float* __restrict__ b3,
    void* __restrict__ lo_out,
    const unsigned short* __restrict__ AF)
{
    const int W = 1 << LOGW, Wp = W + 16, XS = W / 16, RS = 16 * Wp;
    const int Wo = W >> 1, Wpo = Wo + 16, XS2 = Wo / 16;
    const int bandsPerN = XS * (W / 8);
    int n = blockIdx.x & 7;
    int q = blockIdx.x >> 3;
    int t = threadIdx.x, wv = t >> 6, l = t & 63;

    if (q < bandsPerN) {
        int xseg = q & (XS - 1), yq = q >> (LOGW - 4);
        int j = l & 31, pg = j >> 4, c = j & 15, kb = (l >> 5) * 8, hi = l >> 5;
        int x0 = xseg * 16;
        int ybase = (yq * 4 + wv) * 2;

        short8v A[9];
        #pragma unroll
        for (int dy = 0; dy < 9; ++dy)
            A[dy] = *(const short8v*)(AF + ((size_t)(dy * 64 + l)) * 8);

        #pragma unroll 1
        for (int ty = 0; ty < 2; ++ty) {
            int y = ybase + ty;
            const unsigned short* base =
                in + ((size_t)(n * Wp + y + 4) * 16 + c) * Wp + x0 + pg * 8 + kb + 4;
            f32x16 acc = {};
            #pragma unroll
            for (int dy = 0; dy < 9; ++dy) {
                short8v B = *(const short8v*)(base + (size_t)dy * RS);
                acc = MFMA32(A[dy], B, acc, 0, 0, 0);
            }
            size_t ob = ((size_t)(n * W + y) * W + x0 + pg * 8) * 16 + c;
            #pragma unroll
            for (int rr = 0; rr < 4; ++rr) {
                size_t o = ob + (size_t)(rr + 4 * hi) * 16;
                nt_storef(b0 + o, acc[rr]);
                nt_storef(b1 + o, acc[4 + rr]);
                nt_storef(b2 + o, acc[8 + rr]);
                nt_storef(b3 + o, acc[12 + rr]);
            }
        }
    } else {
        int q2 = q - bandsPerN;
        int xseg = q2 & (XS2 - 1), yq = q2 >> (LOGW - 5);
        int m = l & 15, g = l >> 4, kb = g * 8;
        int x0 = xseg * 16;
        int ybase = (yq * 4 + wv) * 2;
        int off2 = (g < 2) ? 32 : 0;

        #pragma unroll 1
        for (int ty = 0; ty < 2; ++ty) {
            int yo = ybase + ty;
            const unsigned short* base =
                in + ((size_t)(n * Wp + 2 * yo) * 16 + m) * Wp + 2 * x0 + kb;
            f32x4 aA = {0, 0, 0, 0}, aB = {0, 0, 0, 0};
            #pragma unroll
            for (int dy = 0; dy < 17; ++dy) {
                short8v A1 = *(const short8v*)(AF + ((size_t)((19 + dy) * 64 + l)) * 8);
                short8v A2 = *(const short8v*)(AF + ((size_t)((36 + dy) * 64 + l)) * 8);
                short8v B1 = *(const short8v*)(base + (size_t)dy * RS);
                short8v B2 = *(const short8v*)(base + (size_t)dy * RS + off2);
                aA = MFMA16(A1, B1, aA, 0, 0, 0);
                aB = MFMA16(A2, B2, aB, 0, 0, 0);
            }
            f32x4 acc = aA + aB;
            if (OUTF32) {
                float* o = (float*)lo_out;
                size_t ob = ((size_t)(n * Wo + yo) * Wo + x0 + g * 4) * 16 + m;
                #pragma unroll
                for (int r = 0; r < 4; ++r) nt_storef(o + ob + (size_t)r * 16, acc[r]);
            } else {
                unsigned short* o = (unsigned short*)lo_out;
                size_t lb = ((size_t)(n * Wpo + yo + 8) * 16 + m) * Wpo + (x0 + 8 + g * 4);
                *(unsigned*)(o + lb)     = pack2(acc[0], acc[1]);
                *(unsigned*)(o + lb + 2) = pack2(acc[2], acc[3]);
            }
        }
    }
}

// ---------------------------------------------------------------- launch

extern "C" void kernel_launch(void* const* d_in, const int* in_sizes, int n_in,
                              void* d_out, int out_size, void* d_ws, size_t ws_size,
                              hipStream_t stream) {
    const float* image   = (const float*)d_in[0];
    const float* lo0filt = (const float*)d_in[1];
    const float* hi0filt = (const float*)d_in[2];
    const float* lofilt  = (const float*)d_in[3];
    const float* bfilts  = (const float*)d_in[4];
    float* out = (float*)d_out;

    const int N = 8, C = 16;
    size_t sz[5];
    const int Ws[5] = {256, 128, 64, 32, 16};
    for (int s = 0; s < 5; ++s) sz[s] = (size_t)N * Ws[s] * Ws[s] * C;

    // Workspace (ushort units): AF table, IMG CX (pad4), L0..L3 CX (pad8).
    unsigned short* wsu = (unsigned short*)d_ws;
    unsigned short* AF  = wsu;                       // 53*64*8 -> pad to 32768
    unsigned short* IMG = AF + 32768;
    unsigned short* L0 = IMG + (size_t)N * 264 * 16 * 264;
    unsigned short* L1 = L0 + (size_t)N * 272 * 16 * 272;
    unsigned short* L2 = L1 + (size_t)N * 144 * 16 * 144;
    unsigned short* L3 = L2 + (size_t)N * 80 * 16 * 80;

    // Output layout (reversed pyramid, flat):
    // [ lo_final | s=3 b=3..0 | s=2 b=3..0 | s=1 b=3..0 | s=0 b=3..0 | hi0 ]
    float* out_lofinal = out;
    size_t o = sz[4];
    float* band_ptr[4][4];
    for (int s = 3; s >= 0; --s)
        for (int b = 3; b >= 0; --b) { band_ptr[s][b] = out + o; o += sz[s]; }
    float* out_hi0 = out + o;

    prep_all<<<3150, 256, 0, stream>>>(
        bfilts, hi0filt, lo0filt, lofilt, AF, L0, L1, L2, L3,
        (const float4*)image, IMG);
    dual_mfma32<<<2048, 256, 0, stream>>>(IMG, out_hi0, L0, AF);
    scale_comb<8, false><<<8 * (512 + 128), 256, 0, stream>>>(
        L0, band_ptr[0][0], band_ptr[0][1], band_ptr[0][2], band_ptr[0][3],
        (void*)L1, AF);
    scale_comb<7, false><<<8 * (128 + 32), 256, 0, stream>>>(
        L1, band_ptr[1][0], band_ptr[1][1], band_ptr[1][2], band_ptr[1][3],
        (void*)L2, AF);
    scale_comb<6, false><<<8 * (32 + 8), 256, 0, stream>>>(
        L2, band_ptr[2][0], band_ptr[2][1], band_ptr[2][2], band_ptr[2][3],
        (void*)L3, AF);
    scale_comb<5, true><<<8 * (8 + 2), 256, 0, stream>>>(
        L3, band_ptr[3][0], band_ptr[3][1], band_ptr[3][2], band_ptr[3][3],
        (void*)out_lofinal, AF);
}

// Round 20
// 116.758 us; speedup vs baseline: 1.5960x; 1.0716x over previous
//
#include <hip/hip_runtime.h>

// Steerable pyramid via MFMA, fp32 I/O, bf16 compute (threshold = 2% of
// per-output absmax; bf16 error 16384 << 46202, verified r12-r19).
// CX layout for staged images: [n][y][c 16][x] bf16, zero-padded.
// Core (r15): 9-tap convs on mfma_f32_32x32x16_bf16 with fused M
// (bands: 4 bands x 8 px; dual: 2 rows x 2 filters x 8 px; K=16 window),
// down17 on 16x16x32 k-split. D map: col=l&31, row=(reg&3)+8(reg>>2)+4(l>>5).
// r17/r18: no __launch_bounds__ min-waves clamps; clamp-free scale_comb
// fusion at all scales (6 launches). r19: 2 tiles/wave, grid x2.
// r20: FULL unroll of the 2-tile loops (was unroll 1) so the compiler
// hoists tile-1 B-loads into tile-0's MFMA shadow (in-wave latency
// hiding); down path shares A-table loads across tiles; pack2 store
// pairs merged into single 8B uint2 stores.

typedef __attribute__((ext_vector_type(8))) short short8v;
typedef __attribute__((ext_vector_type(4))) float f32x4;
typedef __attribute__((ext_vector_type(16))) float f32x16;

static __device__ __forceinline__ unsigned short f2bf(float f) {
    union { float f; unsigned u; } v; v.f = f;
    unsigned u = v.u;
    u += 0x7fffu + ((u >> 16) & 1u);
    return (unsigned short)(u >> 16);
}

static __device__ __forceinline__ unsigned pack2(float a, float b) {
    return (unsigned)f2bf(a) | ((unsigned)f2bf(b) << 16);
}

static __device__ __forceinline__ void nt_storef(float* p, float v) {
    __builtin_nontemporal_store(v, p);
}

// AF fragment table rows (entry = short8v per lane, row*64+l):
// [0..8] bands32 dy | [9..18] dual32 i | [19..35] down A1 | [36..52] down A2

// ---------------------------------------------------------------- prep

static __device__ __forceinline__ void do_build_frags(
    const float* bf, const float* fh, const float* fl, const float* lfilt,
    unsigned short* AF, int id)
{
    if (id >= 53 * 64) return;
    int row = id >> 6, l = id & 63;
    short8v a;
    if (row < 9) {
        int dy = row;
        int m = l & 31, f = m >> 3, p = m & 7, kb = (l >> 5) * 8;
        #pragma unroll
        for (int i = 0; i < 8; ++i) {
            int d = kb + i - p;
            a[i] = (short)((d >= 0 && d < 9) ? f2bf(bf[f * 81 + dy * 9 + d]) : 0);
        }
    } else if (row < 19) {
        int is = row - 9;
        int m = l & 31, ry = m >> 4, f = (m >> 3) & 1, p = m & 7, kb = (l >> 5) * 8;
        int dy = is - ry;
        const float* fr = f ? fl : fh;
        #pragma unroll
        for (int i = 0; i < 8; ++i) {
            int dx = kb + i - p;
            bool ok = (dy >= 0 && dy < 9) && (dx >= 0 && dx < 9);
            a[i] = (short)(ok ? f2bf(fr[dy * 9 + dx]) : 0);
        }
    } else if (row < 36) {
        int dy = row - 19;
        int m = l & 15, kb = (l >> 4) * 8;
        #pragma unroll
        for (int i = 0; i < 8; ++i) {
            int d = kb + i - 2 * m;
            a[i] = (short)((d >= 0 && d < 17) ? f2bf(lfilt[dy * 17 + d]) : 0);
        }
    } else {
        int dy = row - 36;
        int m = l & 15, kb = (l >> 4) * 8;
        #pragma unroll
        for (int i = 0; i < 8; ++i) {
            int d = 32 + kb + i - 2 * m;
            a[i] = (short)((d >= 0 && d < 17) ? f2bf(lfilt[dy * 17 + d]) : 0);
        }
    }
    *(short8v*)(AF + (size_t)id * 8) = a;
}

static __device__ __forceinline__ void zero_cx_vec(
    unsigned short* buf, int W, int id)
{
    int Wp = W + 16, Wv = Wp >> 3;
    int rowT = 16 * 16 * Wv;
    int perN = rowT + W * 32;
    int n = id / perN;
    int r = id - n * perN;
    int y, c, xv;
    if (r < rowT) {
        int ry = r / (16 * Wv);
        int rem = r - ry * (16 * Wv);
        c = rem / Wv;
        xv = rem - c * Wv;
        y = (ry < 8) ? ry : ry + W;
    } else {
        int r2 = r - rowT;
        y = 8 + (r2 >> 5);
        int rem = r2 & 31;
        c = rem >> 1;
        xv = (rem & 1) ? (Wv - 1) : 0;
    }
    short8v z = {0, 0, 0, 0, 0, 0, 0, 0};
    *(short8v*)(buf + ((size_t)(n * Wp + y) * 16 + c) * Wp + xv * 8) = z;
}

// prep_all: [0,14) build_frags | [14,1038) zero_pads | [1038,3150) img_to_cx.
__global__ __launch_bounds__(256) void prep_all(
    const float* __restrict__ bf, const float* __restrict__ fh,
    const float* __restrict__ fl, const float* __restrict__ lfilt,
    unsigned short* __restrict__ AF,
    unsigned short* __restrict__ L0, unsigned short* __restrict__ L1,
    unsigned short* __restrict__ L2, unsigned short* __restrict__ L3,
    const float4* __restrict__ src4, unsigned short* __restrict__ IMG)
{
    __shared__ unsigned short lds[16][264];
    int b = blockIdx.x, t = threadIdx.x;
    if (b < 14) {
        do_build_frags(bf, fh, fl, lfilt, AF, b * 256 + t);
    } else if (b < 1038) {
        int zb = b - 14;
        if (zb < 528)      zero_cx_vec(L0, 256, zb * 256 + t);
        else if (zb < 800) zero_cx_vec(L1, 128, (zb - 528) * 256 + t);
        else if (zb < 944) zero_cx_vec(L2, 64,  (zb - 800) * 256 + t);
        else               zero_cx_vec(L3, 32,  (zb - 944) * 256 + t);
    } else {
        int ib = b - 1038;                   // 2112 = 8 * 264
        int n = ib & 7;
        int yp = ib >> 3;
        int y = yp - 4;
        unsigned short* drow = IMG + ((size_t)(n * 264 + yp) * 16) * 264;
        if ((unsigned)y < 256u) {
            for (int task = t; task < 1056; task += 256) {
                int px = task >> 2, cg = task & 3;
                int xs = px - 4;
                bool ok = (unsigned)xs < 256u;
                int xc = min(max(xs, 0), 255);
                float4 v = src4[((size_t)(n * 256 + y) * 256 + xc) * 4 + cg];
                lds[cg * 4 + 0][px] = (unsigned short)(ok ? f2bf(v.x) : 0);
                lds[cg * 4 + 1][px] = (unsigned short)(ok ? f2bf(v.y) : 0);
                lds[cg * 4 + 2][px] = (unsigned short)(ok ? f2bf(v.z) : 0);
                lds[cg * 4 + 3][px] = (unsigned short)(ok ? f2bf(v.w) : 0);
            }
            __syncthreads();
            for (int task = t; task < 528; task += 256) {
                int c = task / 33, xg = task - c * 33;
                short8v v = *(const short8v*)&lds[c][xg * 8];
                *(short8v*)(drow + (size_t)c * 264 + xg * 8) = v;
            }
        } else {
            short8v z = {0, 0, 0, 0, 0, 0, 0, 0};
            for (int task = t; task < 528; task += 256) {
                int c = task / 33, xg = task - c * 33;
                *(short8v*)(drow + (size_t)c * 264 + xg * 8) = z;
            }
        }
    }
}

// ---------------------------------------------------------------- MFMA convs

#define MFMA16 __builtin_amdgcn_mfma_f32_16x16x32_bf16
#define MFMA32 __builtin_amdgcn_mfma_f32_32x32x16_bf16

// hi0 + lo0 from IMG CX (pad 4), 32x32x16, M = 2 rows x 2 filt x 8 px.
// grid 2048: n=b&7, q=b>>3 (256/img): xseg=q&15, yq=q>>4 in [0,16).
// 2 y-pair tiles per wave, FULLY UNROLLED.
__global__ __launch_bounds__(256) void dual_mfma32(
    const unsigned short* __restrict__ img,
    float* __restrict__ hi0, unsigned short* __restrict__ lo0,
    const unsigned short* __restrict__ AF)
{
    const int RS = 16 * 264;
    int n = blockIdx.x & 7;
    int q = blockIdx.x >> 3;
    int xseg = q & 15, yq = q >> 4;
    int t = threadIdx.x, wv = t >> 6, l = t & 63;
    int j = l & 31, pg = j >> 4, c = j & 15, kb = (l >> 5) * 8, hi = l >> 5;
    int x0 = xseg * 16;
    int pbase = (yq * 4 + wv) * 2;

    short8v A[10];
    #pragma unroll
    for (int i = 0; i < 10; ++i)
        A[i] = *(const short8v*)(AF + ((size_t)((9 + i) * 64 + l)) * 8);

    #pragma unroll
    for (int tp = 0; tp < 2; ++tp) {
        int y = (pbase + tp) * 2;
        const unsigned short* base =
            img + ((size_t)(n * 264 + y) * 16 + c) * 264 + x0 + pg * 8 + kb;
        f32x16 acc = {};
        #pragma unroll
        for (int i = 0; i < 10; ++i) {
            short8v B = *(const short8v*)(base + (size_t)i * RS);
            acc = MFMA32(A[i], B, acc, 0, 0, 0);
        }
        #pragma unroll
        for (int ry = 0; ry < 2; ++ry) {
            size_t hb = ((size_t)(n * 256 + y + ry) * 256 + x0 + pg * 8) * 16 + c;
            #pragma unroll
            for (int rr = 0; rr < 4; ++rr) {
                int r = ry * 8 + rr;
                int p = rr + 4 * hi;
                nt_storef(hi0 + hb + (size_t)p * 16, acc[r]);
            }
            size_t lb = ((size_t)(n * 272 + y + ry + 8) * 16 + c) * 272
                        + (x0 + pg * 8 + 4 * hi + 8);
            int r0 = ry * 8 + 4;
            uint2 pk = make_uint2(pack2(acc[r0], acc[r0 + 1]),
                                  pack2(acc[r0 + 2], acc[r0 + 3]));
            *(uint2*)(lo0 + lb) = pk;
        }
    }
}

// Fused per-scale (clamp-free), 2 tiles/wave FULLY UNROLLED:
// q < bandsPerN -> bands (32x32x16, A preloaded);
// else down17 (16x16x32, A loaded once from L1-hot AF, shared by tiles).
// bandsPerN = (W/16)*(W/8); downPerN = (Wo/16)*(Wo/8).
template <int LOGW, bool OUTF32>
__global__ __launch_bounds__(256) void scale_comb(
    const unsigned short* __restrict__ in,
    float* __restrict__ b0, float* __restrict__ b1,
    float* __restrict__ b2, float* __restrict__ b3,
    void* __restrict__ lo_out,
    const unsigned short* __restrict__ AF)
{
    const int W = 1 << LOGW, Wp = W + 16, XS = W / 16, RS = 16 * Wp;
    const int Wo = W >> 1, Wpo = Wo + 16, XS2 = Wo / 16;
    const int bandsPerN = XS * (W / 8);
    int n = blockIdx.x & 7;
    int q = blockIdx.x >> 3;
    int t = threadIdx.x, wv = t >> 6, l = t & 63;

    if (q < bandsPerN) {
        int xseg = q & (XS - 1), yq = q >> (LOGW - 4);
        int j = l & 31, pg = j >> 4, c = j & 15, kb = (l >> 5) * 8, hi = l >> 5;
        int x0 = xseg * 16;
        int ybase = (yq * 4 + wv) * 2;

        short8v A[9];
        #pragma unroll
        for (int dy = 0; dy < 9; ++dy)
            A[dy] = *(const short8v*)(AF + ((size_t)(dy * 64 + l)) * 8);

        #pragma unroll
        for (int ty = 0; ty < 2; ++ty) {
            int y = ybase + ty;
            const unsigned short* base =
                in + ((size_t)(n * Wp + y + 4) * 16 + c) * Wp + x0 + pg * 8 + kb + 4;
            f32x16 acc = {};
            #pragma unroll
            for (int dy = 0; dy < 9; ++dy) {
                short8v B = *(const short8v*)(base + (size_t)dy * RS);
                acc = MFMA32(A[dy], B, acc, 0, 0, 0);
            }
            size_t ob = ((size_t)(n * W + y) * W + x0 + pg * 8) * 16 + c;
            #pragma unroll
            for (int rr = 0; rr < 4; ++rr) {
                size_t o = ob + (size_t)(rr + 4 * hi) * 16;
                nt_storef(b0 + o, acc[rr]);
                nt_storef(b1 + o, acc[4 + rr]);
                nt_storef(b2 + o, acc[8 + rr]);
                nt_storef(b3 + o, acc[12 + rr]);
            }
        }
    } else {
        int q2 = q - bandsPerN;
        int xseg = q2 & (XS2 - 1), yq = q2 >> (LOGW - 5);
        int m = l & 15, g = l >> 4, kb = g * 8;
        int x0 = xseg * 16;
        int ybase = (yq * 4 + wv) * 2;
        int off2 = (g < 2) ? 32 : 0;

        short8v A1[17], A2[17];
        #pragma unroll
        for (int dy = 0; dy < 17; ++dy) {
            A1[dy] = *(const short8v*)(AF + ((size_t)((19 + dy) * 64 + l)) * 8);
            A2[dy] = *(const short8v*)(AF + ((size_t)((36 + dy) * 64 + l)) * 8);
        }

        #pragma unroll
        for (int ty = 0; ty < 2; ++ty) {
            int yo = ybase + ty;
            const unsigned short* base =
                in + ((size_t)(n * Wp + 2 * yo) * 16 + m) * Wp + 2 * x0 + kb;
            f32x4 aA = {0, 0, 0, 0}, aB = {0, 0, 0, 0};
            #pragma unroll
            for (int dy = 0; dy < 17; ++dy) {
                short8v B1 = *(const short8v*)(base + (size_t)dy * RS);
                short8v B2 = *(const short8v*)(base + (size_t)dy * RS + off2);
                aA = MFMA16(A1[dy], B1, aA, 0, 0, 0);
                aB = MFMA16(A2[dy], B2, aB, 0, 0, 0);
            }
            f32x4 acc = aA + aB;
            if (OUTF32) {
                float* o = (float*)lo_out;
                size_t ob = ((size_t)(n * Wo + yo) * Wo + x0 + g * 4) * 16 + m;
                #pragma unroll
                for (int r = 0; r < 4; ++r) nt_storef(o + ob + (size_t)r * 16, acc[r]);
            } else {
                unsigned short* o = (unsigned short*)lo_out;
                size_t lb = ((size_t)(n * Wpo + yo + 8) * 16 + m) * Wpo + (x0 + 8 + g * 4);
                uint2 pk = make_uint2(pack2(acc[0], acc[1]),
                                      pack2(acc[2], acc[3]));
                *(uint2*)(o + lb) = pk;
            }
        }
    }
}

// ---------------------------------------------------------------- launch

extern "C" void kernel_launch(void* const* d_in, const int* in_sizes, int n_in,
                              void* d_out, int out_size, void* d_ws, size_t ws_size,
                              hipStream_t stream) {
    const float* image   = (const float*)d_in[0];
    const float* lo0filt = (const float*)d_in[1];
    const float* hi0filt = (const float*)d_in[2];
    const float* lofilt  = (const float*)d_in[3];
    const float* bfilts  = (const float*)d_in[4];
    float* out = (float*)d_out;

    const int N = 8, C = 16;
    size_t sz[5];
    const int Ws[5] = {256, 128, 64, 32, 16};
    for (int s = 0; s < 5; ++s) sz[s] = (size_t)N * Ws[s] * Ws[s] * C;

    // Workspace (ushort units): AF table, IMG CX (pad4), L0..L3 CX (pad8).
    unsigned short* wsu = (unsigned short*)d_ws;
    unsigned short* AF  = wsu;                       // 53*64*8 -> pad to 32768
    unsigned short* IMG = AF + 32768;
    unsigned short* L0 = IMG + (size_t)N * 264 * 16 * 264;
    unsigned short* L1 = L0 + (size_t)N * 272 * 16 * 272;
    unsigned short* L2 = L1 + (size_t)N * 144 * 16 * 144;
    unsigned short* L3 = L2 + (size_t)N * 80 * 16 * 80;

    // Output layout (reversed pyramid, flat):
    // [ lo_final | s=3 b=3..0 | s=2 b=3..0 | s=1 b=3..0 | s=0 b=3..0 | hi0 ]
    float* out_lofinal = out;
    size_t o = sz[4];
    float* band_ptr[4][4];
    for (int s = 3; s >= 0; --s)
        for (int b = 3; b >= 0; --b) { band_ptr[s][b] = out + o; o += sz[s]; }
    float* out_hi0 = out + o;

    prep_all<<<3150, 256, 0, stream>>>(
        bfilts, hi0filt, lo0filt, lofilt, AF, L0, L1, L2, L3,
        (const float4*)image, IMG);
    dual_mfma32<<<2048, 256, 0, stream>>>(IMG, out_hi0, L0, AF);
    scale_comb<8, false><<<8 * (512 + 128), 256, 0, stream>>>(
        L0, band_ptr[0][0], band_ptr[0][1], band_ptr[0][2], band_ptr[0][3],
        (void*)L1, AF);
    scale_comb<7, false><<<8 * (128 + 32), 256, 0, stream>>>(
        L1, band_ptr[1][0], band_ptr[1][1], band_ptr[1][2], band_ptr[1][3],
        (void*)L2, AF);
    scale_comb<6, false><<<8 * (32 + 8), 256, 0, stream>>>(
        L2, band_ptr[2][0], band_ptr[2][1], band_ptr[2][2], band_ptr[2][3],
        (void*)L3, AF);
    scale_comb<5, true><<<8 * (8 + 2), 256, 0, stream>>>(
        L3, band_ptr[3][0], band_ptr[3][1], band_ptr[3][2], band_ptr[3][3],
        (void*)out_lofinal, AF);
}